// Round 4
// baseline (5562.023 us; speedup 1.0000x reference)
//
#include <hip/hip_runtime.h>
#include <math.h>

#define NL 4096      // 2*N_VARS literals
#define NV 2048      // N_VARS
#define NC 8192      // N_CLAUSES
#define DIM 128
#define NG 512       // 4*DIM LSTM gates
#define NROUNDS 26

// segmented build (deterministic, no atomics), then merged to compact lists
#define CSEG 32
#define CSEGLEN 128      // NL/CSEG
#define CSEGCAP 12
#define LSEG 32
#define LSEGLEN 256      // NC/LSEG
#define LSEGCAP 16
#define CCAP 32          // Poisson(6.1): P(>32) ~ 1e-16
#define LCAP 48          // Poisson(12.3): P(>48) ~ 1e-15

__device__ __forceinline__ float sigf(float x){ return 1.0f/(1.0f+expf(-x)); }

// ---- generic tiled transpose: dst[C][R] = src[R][C]^T ----------------------
__global__ void k_transpose(const float* __restrict__ src, float* __restrict__ dst,
                            int R, int C){
  __shared__ float t[32][33];
  int cb = blockIdx.x*32, rb = blockIdx.y*32;
  int x = threadIdx.x, y = threadIdx.y;
  for (int i = y; i < 32; i += 8){
    int r = rb+i, c = cb+x;
    if (r < R && c < C) t[i][x] = src[(size_t)r*C + c];
  }
  __syncthreads();
  for (int i = y; i < 32; i += 8){
    int c = cb+i, r = rb+x;
    if (c < C && r < R) dst[(size_t)c*R + r] = t[x][i];
  }
}

// gate-quad permute: dst[koff+k][4d+g] = W[g*128+d][k]   (W is [512][K] row-major)
__global__ void k_permq(const float* __restrict__ W, int K,
                        float* __restrict__ dst, int koff){
  int idx = blockIdx.x*blockDim.x + threadIdx.x;
  if (idx >= K*NG) return;
  int k = idx >> 9, j = idx & (NG-1);
  int g = j & 3, d = j >> 2;
  dst[(size_t)(koff+k)*NG + j] = W[(size_t)(g*DIM+d)*K + k];
}

// bias permute: bq[4d+g] = bih[g*128+d] + bhh[g*128+d]
__global__ void k_permb(const float* __restrict__ bih, const float* __restrict__ bhh,
                        float* __restrict__ bq){
  int j = blockIdx.x*blockDim.x + threadIdx.x;
  if (j >= NG) return;
  int g = j & 3, d = j >> 2;
  bq[j] = bih[g*DIM+d] + bhh[g*DIM+d];
}

// ---- adjacency build -------------------------------------------------------
__global__ void k_build_cseg(const float* __restrict__ adj,
                             int* __restrict__ scnt, int* __restrict__ slst){
  int idx = blockIdx.x*blockDim.x + threadIdx.x;   // [0, NC*CSEG)
  int c = idx & (NC-1);
  int s = idx >> 13;
  if (s >= CSEG) return;
  int base = s*CSEGLEN;
  int* out = slst + ((size_t)c*CSEG + s)*CSEGCAP;
  int n = 0;
  for (int i = 0; i < CSEGLEN; ++i){
    float v = adj[(size_t)(base+i)*NC + c];
    if (v != 0.0f){ if (n < CSEGCAP) out[n] = base+i; ++n; }
  }
  scnt[c*CSEG+s] = n < CSEGCAP ? n : CSEGCAP;
}

__global__ void k_build_lseg(const float* __restrict__ adj,
                             int* __restrict__ scnt, int* __restrict__ slst){
  int gtid = blockIdx.x*blockDim.x + threadIdx.x;
  int wid  = gtid >> 6;
  int lane = threadIdx.x & 63;
  int l = wid >> 5;
  int s = wid & (LSEG-1);
  if (l >= NL) return;
  int base = s*LSEGLEN;
  int* out = slst + ((size_t)l*LSEG + s)*LSEGCAP;
  int n = 0;
  for (int it = 0; it < LSEGLEN/64; ++it){
    int c = base + it*64 + lane;
    float v = adj[(size_t)l*NC + c];
    unsigned long long m = __ballot(v != 0.0f);
    if (v != 0.0f){
      int pos = n + __popcll(m & ((1ull<<lane)-1ull));
      if (pos < LSEGCAP) out[pos] = c;
    }
    n += __popcll(m);
  }
  if (lane == 0) scnt[l*LSEG+s] = n < LSEGCAP ? n : LSEGCAP;
}

__global__ void k_merge_c(const int* __restrict__ scnt, const int* __restrict__ slst,
                          int* __restrict__ cnt, int* __restrict__ lst){
  int c = blockIdx.x*blockDim.x + threadIdx.x;
  if (c >= NC) return;
  int n = 0;
  for (int s = 0; s < CSEG; ++s){
    int m = scnt[c*CSEG+s];
    const int* in = slst + ((size_t)c*CSEG+s)*CSEGCAP;
    for (int t = 0; t < m; ++t){ if (n < CCAP) lst[(size_t)c*CCAP+n] = in[t]; ++n; }
  }
  cnt[c] = n < CCAP ? n : CCAP;
}

__global__ void k_merge_l(const int* __restrict__ scnt, const int* __restrict__ slst,
                          int* __restrict__ cnt, int* __restrict__ lst){
  int l = blockIdx.x*blockDim.x + threadIdx.x;
  if (l >= NL) return;
  int n = 0;
  for (int s = 0; s < LSEG; ++s){
    int m = scnt[l*LSEG+s];
    const int* in = slst + ((size_t)l*LSEG+s)*LSEGCAP;
    for (int t = 0; t < m; ++t){ if (n < LCAP) lst[(size_t)l*LCAP+n] = in[t]; ++n; }
  }
  cnt[l] = n < LCAP ? n : LCAP;
}

// ---- state init ------------------------------------------------------------
__global__ void k_init(const float* __restrict__ liw, const float* __restrict__ lib,
                       const float* __restrict__ ciw, const float* __restrict__ cib,
                       float* __restrict__ Lh, float* __restrict__ Lc,
                       float* __restrict__ Ch, float* __restrict__ Cc){
  int idx = blockIdx.x*blockDim.x + threadIdx.x;
  int d = idx & (DIM-1);
  if (idx < NL*DIM){ Lh[idx] = liw[d] + lib[d]; Lc[idx] = 0.0f; }
  if (idx < NC*DIM){ Ch[idx] = ciw[d] + cib[d]; Cc[idx] = 0.0f; }
}

// ---- fused 3-layer MLP, 16 rows/block, 512 threads, k-major weights --------
// thread: 4 cols (quad) x 1 row (slot). Weight loads coalesced.
template<bool RELU>
__device__ __forceinline__ void mlp_layer16(const float (*__restrict__ xs)[DIM],
                                            float (*__restrict__ ys)[DIM],
                                            const float* __restrict__ Wt,   // [DIM][DIM] k-major
                                            const float* __restrict__ B, int tid){
  int j4 = (tid & 31)*4, slot = tid >> 5;
  float a0=0.f, a1=0.f, a2=0.f, a3=0.f;
#pragma unroll 4
  for (int k = 0; k < DIM; k += 4){
    float4 w0 = *(const float4*)&Wt[(size_t)(k+0)*DIM + j4];
    float4 w1 = *(const float4*)&Wt[(size_t)(k+1)*DIM + j4];
    float4 w2 = *(const float4*)&Wt[(size_t)(k+2)*DIM + j4];
    float4 w3 = *(const float4*)&Wt[(size_t)(k+3)*DIM + j4];
    float4 x  = *(const float4*)&xs[slot][k];
    a0 += x.x*w0.x + x.y*w1.x + x.z*w2.x + x.w*w3.x;
    a1 += x.x*w0.y + x.y*w1.y + x.z*w2.y + x.w*w3.y;
    a2 += x.x*w0.z + x.y*w1.z + x.z*w2.z + x.w*w3.z;
    a3 += x.x*w0.w + x.y*w1.w + x.z*w2.w + x.w*w3.w;
  }
  float4 b = *(const float4*)&B[j4];
  float4 v = make_float4(a0+b.x, a1+b.y, a2+b.z, a3+b.w);
  if (RELU){
    v.x = fmaxf(v.x,0.f); v.y = fmaxf(v.y,0.f);
    v.z = fmaxf(v.z,0.f); v.w = fmaxf(v.w,0.f);
  }
  *(float4*)&ys[slot][j4] = v;
}

__global__ __launch_bounds__(512, 4)
void k_mlp3(const float* __restrict__ in, float* __restrict__ out,
            const float* __restrict__ w1t, const float* __restrict__ b1,
            const float* __restrict__ w2t, const float* __restrict__ b2,
            const float* __restrict__ w3t, const float* __restrict__ b3){
  __shared__ __align__(16) float xs[16][DIM];
  __shared__ __align__(16) float ys[16][DIM];
  int r0 = blockIdx.x*16;
  int tid = threadIdx.x;
  {
    int row = tid >> 5, c4 = (tid & 31)*4;
    *(float4*)&xs[row][c4] = *(const float4*)&in[(size_t)(r0+row)*DIM + c4];
  }
  __syncthreads();
  mlp_layer16<true >(xs, ys, w1t, b1, tid);
  __syncthreads();
  mlp_layer16<true >(ys, xs, w2t, b2, tid);
  __syncthreads();
  mlp_layer16<false>(xs, ys, w3t, b3, tid);
  __syncthreads();
  {
    int row = tid >> 5, c4 = (tid & 31)*4;
    *(float4*)&out[(size_t)(r0+row)*DIM + c4] = *(const float4*)&ys[row][c4];
  }
}

// ---- clause side: gather + LSTM, gate-quad in-register ----------------------
// 16 rows/block, 512 threads: d = tid&127, slot = tid>>7 owns 4 rows.
__global__ __launch_bounds__(512, 4)
void k_clause_upd(const float* __restrict__ Lpre,
                  const int* __restrict__ cnt, const int* __restrict__ lst,
                  float* __restrict__ Ch, float* __restrict__ Cc,
                  const float* __restrict__ Wq,    // [256][512] k-major, quad-permuted
                  const float* __restrict__ bq){   // [512] quad-permuted
  __shared__ __align__(16) float xs[16][256];   // [LC_msg | h]
  int c0 = blockIdx.x*16;
  int tid = threadIdx.x;
  int d = tid & 127, slot = tid >> 7;
  {
    int row = tid >> 5, c4 = (tid & 31)*4;
    *(float4*)&xs[row][DIM + c4] = *(const float4*)&Ch[(size_t)(c0+row)*DIM + c4];
  }
#pragma unroll
  for (int rr = 0; rr < 4; ++rr){
    int r = slot*4 + rr;
    int c = c0 + r;
    float s = 0.f;
    int n = cnt[c];
    const int* ls = lst + (size_t)c*CCAP;
    for (int t = 0; t < n; ++t) s += Lpre[(size_t)ls[t]*DIM + d];
    xs[r][d] = s;
  }
  __syncthreads();
  float acc[4][4];
#pragma unroll
  for (int rr = 0; rr < 4; ++rr)
#pragma unroll
    for (int g = 0; g < 4; ++g) acc[rr][g] = 0.f;
  const float* wp = Wq + 4*d;
  const float* xrow = &xs[slot*4][0];
#pragma unroll 2
  for (int k = 0; k < 256; k += 4){
    float4 w0 = *(const float4*)&wp[(size_t)(k+0)*NG];
    float4 w1 = *(const float4*)&wp[(size_t)(k+1)*NG];
    float4 w2 = *(const float4*)&wp[(size_t)(k+2)*NG];
    float4 w3 = *(const float4*)&wp[(size_t)(k+3)*NG];
#pragma unroll
    for (int rr = 0; rr < 4; ++rr){
      float4 x = *(const float4*)&xrow[(size_t)rr*256 + k];
      acc[rr][0] += x.x*w0.x + x.y*w1.x + x.z*w2.x + x.w*w3.x;
      acc[rr][1] += x.x*w0.y + x.y*w1.y + x.z*w2.y + x.w*w3.y;
      acc[rr][2] += x.x*w0.z + x.y*w1.z + x.z*w2.z + x.w*w3.z;
      acc[rr][3] += x.x*w0.w + x.y*w1.w + x.z*w2.w + x.w*w3.w;
    }
  }
  float4 b = *(const float4*)&bq[4*d];
#pragma unroll
  for (int rr = 0; rr < 4; ++rr){
    int c = c0 + slot*4 + rr;
    float ig = acc[rr][0]+b.x, fg = acc[rr][1]+b.y;
    float gg = acc[rr][2]+b.z, og = acc[rr][3]+b.w;
    size_t off = (size_t)c*DIM + d;
    float cn = sigf(fg)*Cc[off] + sigf(ig)*tanhf(gg);
    float hn = sigf(og)*tanhf(cn);
    Cc[off] = cn;
    Ch[off] = hn;
  }
}

// ---- literal side: gather + flip + LSTM, gate-quad in-register --------------
__global__ __launch_bounds__(512, 4)
void k_lit_upd(const float* __restrict__ Cpre,
               const int* __restrict__ cnt, const int* __restrict__ lst,
               const float* __restrict__ Lh_old, float* __restrict__ Lh_new,
               float* __restrict__ Lc,
               const float* __restrict__ Wq,     // [384][512] k-major, quad-permuted
               const float* __restrict__ bq){
  __shared__ __align__(16) float xs[16][384];   // [CL_msg | L_flip | h]
  int l0 = blockIdx.x*16;
  int tid = threadIdx.x;
  int d = tid & 127, slot = tid >> 7;
  {
    int row = tid >> 5, c4 = (tid & 31)*4;
    *(float4*)&xs[row][256 + c4] = *(const float4*)&Lh_old[(size_t)(l0+row)*DIM + c4];
    int fl = (l0 + row + NV) & (NL-1);
    *(float4*)&xs[row][DIM + c4] = *(const float4*)&Lh_old[(size_t)fl*DIM + c4];
  }
#pragma unroll
  for (int rr = 0; rr < 4; ++rr){
    int r = slot*4 + rr;
    int l = l0 + r;
    float s = 0.f;
    int n = cnt[l];
    const int* ls = lst + (size_t)l*LCAP;
    for (int t = 0; t < n; ++t) s += Cpre[(size_t)ls[t]*DIM + d];
    xs[r][d] = s;
  }
  __syncthreads();
  float acc[4][4];
#pragma unroll
  for (int rr = 0; rr < 4; ++rr)
#pragma unroll
    for (int g = 0; g < 4; ++g) acc[rr][g] = 0.f;
  const float* wp = Wq + 4*d;
  const float* xrow = &xs[slot*4][0];
#pragma unroll 2
  for (int k = 0; k < 384; k += 4){
    float4 w0 = *(const float4*)&wp[(size_t)(k+0)*NG];
    float4 w1 = *(const float4*)&wp[(size_t)(k+1)*NG];
    float4 w2 = *(const float4*)&wp[(size_t)(k+2)*NG];
    float4 w3 = *(const float4*)&wp[(size_t)(k+3)*NG];
#pragma unroll
    for (int rr = 0; rr < 4; ++rr){
      float4 x = *(const float4*)&xrow[(size_t)rr*384 + k];
      acc[rr][0] += x.x*w0.x + x.y*w1.x + x.z*w2.x + x.w*w3.x;
      acc[rr][1] += x.x*w0.y + x.y*w1.y + x.z*w2.y + x.w*w3.y;
      acc[rr][2] += x.x*w0.z + x.y*w1.z + x.z*w2.z + x.w*w3.z;
      acc[rr][3] += x.x*w0.w + x.y*w1.w + x.z*w2.w + x.w*w3.w;
    }
  }
  float4 b = *(const float4*)&bq[4*d];
#pragma unroll
  for (int rr = 0; rr < 4; ++rr){
    int l = l0 + slot*4 + rr;
    float ig = acc[rr][0]+b.x, fg = acc[rr][1]+b.y;
    float gg = acc[rr][2]+b.z, og = acc[rr][3]+b.w;
    size_t off = (size_t)l*DIM + d;
    float cn = sigf(fg)*Lc[off] + sigf(ig)*tanhf(gg);
    float hn = sigf(og)*tanhf(cn);
    Lc[off] = cn;
    Lh_new[off] = hn;
  }
}

// ---- vote MLP (128->128->128->1) + logits copy, 8 rows/block ---------------
template<bool RELU>
__device__ __forceinline__ void mlp_layer8v(const float (*__restrict__ xs)[DIM],
                                            float (*__restrict__ ys)[DIM],
                                            const float* __restrict__ Wt,
                                            const float* __restrict__ B, int tid){
  int j4 = (tid & 31)*4, slot = tid >> 5;
  float a0=0.f, a1=0.f, a2=0.f, a3=0.f;
#pragma unroll 4
  for (int k = 0; k < DIM; k += 4){
    float4 w0 = *(const float4*)&Wt[(size_t)(k+0)*DIM + j4];
    float4 w1 = *(const float4*)&Wt[(size_t)(k+1)*DIM + j4];
    float4 w2 = *(const float4*)&Wt[(size_t)(k+2)*DIM + j4];
    float4 w3 = *(const float4*)&Wt[(size_t)(k+3)*DIM + j4];
    float4 x  = *(const float4*)&xs[slot][k];
    a0 += x.x*w0.x + x.y*w1.x + x.z*w2.x + x.w*w3.x;
    a1 += x.x*w0.y + x.y*w1.y + x.z*w2.y + x.w*w3.y;
    a2 += x.x*w0.z + x.y*w1.z + x.z*w2.z + x.w*w3.z;
    a3 += x.x*w0.w + x.y*w1.w + x.z*w2.w + x.w*w3.w;
  }
  float4 b = *(const float4*)&B[j4];
  float4 v = make_float4(a0+b.x, a1+b.y, a2+b.z, a3+b.w);
  if (RELU){
    v.x = fmaxf(v.x,0.f); v.y = fmaxf(v.y,0.f);
    v.z = fmaxf(v.z,0.f); v.w = fmaxf(v.w,0.f);
  }
  *(float4*)&ys[slot][j4] = v;
}

__global__ __launch_bounds__(256, 4)
void k_vote(const float* __restrict__ Lh, float* __restrict__ vote,
            float* __restrict__ dout,
            const float* __restrict__ w1t, const float* __restrict__ b1,
            const float* __restrict__ w2t, const float* __restrict__ b2,
            const float* __restrict__ w3, const float* __restrict__ b3){
  __shared__ __align__(16) float xs[8][DIM];
  __shared__ __align__(16) float ys[8][DIM];
  int r0 = blockIdx.x*8;
  int tid = threadIdx.x;
  {
    int row = tid >> 5, c4 = (tid & 31)*4;
    float4 v = *(const float4*)&Lh[(size_t)(r0+row)*DIM + c4];
    *(float4*)&xs[row][c4] = v;
    *(float4*)&dout[1 + NL + (size_t)(r0+row)*DIM + c4] = v;   // logits out
  }
  __syncthreads();
  mlp_layer8v<true>(xs, ys, w1t, b1, tid);
  __syncthreads();
  mlp_layer8v<true>(ys, xs, w2t, b2, tid);
  __syncthreads();
  int r = tid >> 5, lane32 = tid & 31;
  float4 x = *(const float4*)&xs[r][lane32*4];
  float4 w = *(const float4*)&w3[lane32*4];
  float pp = x.x*w.x + x.y*w.y + x.z*w.z + x.w*w.w;
  pp += __shfl_down(pp, 16, 32);
  pp += __shfl_down(pp, 8, 32);
  pp += __shfl_down(pp, 4, 32);
  pp += __shfl_down(pp, 2, 32);
  pp += __shfl_down(pp, 1, 32);
  if (lane32 == 0){
    float t = pp + b3[0];
    vote[r0+r] = t;
    dout[1 + r0 + r] = t;
  }
}

__global__ void k_mean(const float* __restrict__ vote, float* __restrict__ dout){
  __shared__ float red[256];
  int tid = threadIdx.x;
  float s = 0.f;
  for (int i = tid; i < NL; i += 256) s += vote[i];
  red[tid] = s;
  __syncthreads();
  for (int w = 128; w > 0; w >>= 1){
    if (tid < w) red[tid] += red[tid+w];
    __syncthreads();
  }
  if (tid == 0) dout[0] = red[0] / (float)NL;
}

// ---- host ------------------------------------------------------------------
static inline void launch_transpose(const float* src, float* dst, int R, int C,
                                    hipStream_t stream){
  dim3 g((C+31)/32, (R+31)/32), b(32, 8);
  k_transpose<<<g, b, 0, stream>>>(src, dst, R, C);
}

extern "C" void kernel_launch(void* const* d_in, const int* in_sizes, int n_in,
                              void* d_out, int out_size, void* d_ws, size_t ws_size,
                              hipStream_t stream){
  const float* adj      = (const float*)d_in[0];
  const float* l_init_w = (const float*)d_in[1];
  const float* l_init_b = (const float*)d_in[2];
  const float* c_init_w = (const float*)d_in[3];
  const float* c_init_b = (const float*)d_in[4];
  const float* lmsg_w1  = (const float*)d_in[5];
  const float* lmsg_b1  = (const float*)d_in[6];
  const float* lmsg_w2  = (const float*)d_in[7];
  const float* lmsg_b2  = (const float*)d_in[8];
  const float* lmsg_w3  = (const float*)d_in[9];
  const float* lmsg_b3  = (const float*)d_in[10];
  const float* cmsg_w1  = (const float*)d_in[11];
  const float* cmsg_b1  = (const float*)d_in[12];
  const float* cmsg_w2  = (const float*)d_in[13];
  const float* cmsg_b2  = (const float*)d_in[14];
  const float* cmsg_w3  = (const float*)d_in[15];
  const float* cmsg_b3  = (const float*)d_in[16];
  const float* l_wih    = (const float*)d_in[17];
  const float* l_whh    = (const float*)d_in[18];
  const float* l_bih    = (const float*)d_in[19];
  const float* l_bhh    = (const float*)d_in[20];
  const float* c_wih    = (const float*)d_in[21];
  const float* c_whh    = (const float*)d_in[22];
  const float* c_bih    = (const float*)d_in[23];
  const float* c_bhh    = (const float*)d_in[24];
  const float* lvote_w1 = (const float*)d_in[25];
  const float* lvote_b1 = (const float*)d_in[26];
  const float* lvote_w2 = (const float*)d_in[27];
  const float* lvote_b2 = (const float*)d_in[28];
  const float* lvote_w3 = (const float*)d_in[29];
  const float* lvote_b3 = (const float*)d_in[30];

  char* p = (char*)d_ws;
  auto alloc = [&](size_t bytes) -> void* {
    void* r = (void*)p;
    p += (bytes + 255) & ~(size_t)255;
    return r;
  };
  float* LhA   = (float*)alloc((size_t)NL*DIM*4);
  float* LhB   = (float*)alloc((size_t)NL*DIM*4);
  float* Lc    = (float*)alloc((size_t)NL*DIM*4);
  float* Ch    = (float*)alloc((size_t)NC*DIM*4);
  float* Cc    = (float*)alloc((size_t)NC*DIM*4);
  float* Lpre  = (float*)alloc((size_t)NL*DIM*4);
  float* Cpre  = (float*)alloc((size_t)NC*DIM*4);
  float* vote  = (float*)alloc((size_t)NL*4);
  int* scnt_c  = (int*)alloc((size_t)NC*CSEG*4);
  int* slst_c  = (int*)alloc((size_t)NC*CSEG*CSEGCAP*4);
  int* scnt_l  = (int*)alloc((size_t)NL*LSEG*4);
  int* slst_l  = (int*)alloc((size_t)NL*LSEG*LSEGCAP*4);
  int* ccnt    = (int*)alloc((size_t)NC*4);
  int* clst    = (int*)alloc((size_t)NC*CCAP*4);
  int* lcnt    = (int*)alloc((size_t)NL*4);
  int* llst    = (int*)alloc((size_t)NL*LCAP*4);
  // k-major MLP weights, quad-permuted LSTM weights
  float* lm1t  = (float*)alloc((size_t)DIM*DIM*4);
  float* lm2t  = (float*)alloc((size_t)DIM*DIM*4);
  float* lm3t  = (float*)alloc((size_t)DIM*DIM*4);
  float* cm1t  = (float*)alloc((size_t)DIM*DIM*4);
  float* cm2t  = (float*)alloc((size_t)DIM*DIM*4);
  float* cm3t  = (float*)alloc((size_t)DIM*DIM*4);
  float* vw1t  = (float*)alloc((size_t)DIM*DIM*4);
  float* vw2t  = (float*)alloc((size_t)DIM*DIM*4);
  float* WqC   = (float*)alloc((size_t)256*NG*4);
  float* WqL   = (float*)alloc((size_t)384*NG*4);
  float* bqC   = (float*)alloc((size_t)NG*4);
  float* bqL   = (float*)alloc((size_t)NG*4);
  (void)ws_size; (void)in_sizes; (void)n_in; (void)out_size;

  launch_transpose(lmsg_w1, lm1t, DIM, DIM, stream);
  launch_transpose(lmsg_w2, lm2t, DIM, DIM, stream);
  launch_transpose(lmsg_w3, lm3t, DIM, DIM, stream);
  launch_transpose(cmsg_w1, cm1t, DIM, DIM, stream);
  launch_transpose(cmsg_w2, cm2t, DIM, DIM, stream);
  launch_transpose(cmsg_w3, cm3t, DIM, DIM, stream);
  launch_transpose(lvote_w1, vw1t, DIM, DIM, stream);
  launch_transpose(lvote_w2, vw2t, DIM, DIM, stream);
  k_permq<<<(128*NG)/256, 256, 0, stream>>>(c_wih, 128, WqC, 0);
  k_permq<<<(128*NG)/256, 256, 0, stream>>>(c_whh, 128, WqC, 128);
  k_permq<<<(256*NG)/256, 256, 0, stream>>>(l_wih, 256, WqL, 0);
  k_permq<<<(128*NG)/256, 256, 0, stream>>>(l_whh, 128, WqL, 256);
  k_permb<<<NG/256, 256, 0, stream>>>(c_bih, c_bhh, bqC);
  k_permb<<<NG/256, 256, 0, stream>>>(l_bih, l_bhh, bqL);

  k_build_cseg<<<NC*CSEG/256, 256, 0, stream>>>(adj, scnt_c, slst_c);
  k_build_lseg<<<NL*LSEG*64/256, 256, 0, stream>>>(adj, scnt_l, slst_l);
  k_merge_c<<<NC/256, 256, 0, stream>>>(scnt_c, slst_c, ccnt, clst);
  k_merge_l<<<NL/256, 256, 0, stream>>>(scnt_l, slst_l, lcnt, llst);
  k_init<<<NC*DIM/256, 256, 0, stream>>>(l_init_w, l_init_b, c_init_w, c_init_b,
                                         LhA, Lc, Ch, Cc);

  float* Lh_cur = LhA;
  float* Lh_nxt = LhB;
  for (int r = 0; r < NROUNDS; ++r){
    k_mlp3<<<NL/16, 512, 0, stream>>>(Lh_cur, Lpre,
                                      lm1t, lmsg_b1, lm2t, lmsg_b2, lm3t, lmsg_b3);
    k_clause_upd<<<NC/16, 512, 0, stream>>>(Lpre, ccnt, clst, Ch, Cc, WqC, bqC);
    k_mlp3<<<NC/16, 512, 0, stream>>>(Ch, Cpre,
                                      cm1t, cmsg_b1, cm2t, cmsg_b2, cm3t, cmsg_b3);
    k_lit_upd<<<NL/16, 512, 0, stream>>>(Cpre, lcnt, llst, Lh_cur, Lh_nxt, Lc,
                                         WqL, bqL);
    float* t = Lh_cur; Lh_cur = Lh_nxt; Lh_nxt = t;
  }

  k_vote<<<NL/8, 256, 0, stream>>>(Lh_cur, vote, (float*)d_out,
                                   vw1t, lvote_b1, vw2t, lvote_b2,
                                   lvote_w3, lvote_b3);
  k_mean<<<1, 256, 0, stream>>>(vote, (float*)d_out);
}